// Round 4
// baseline (580.542 us; speedup 1.0000x reference)
//
#include <hip/hip_runtime.h>
#include <hip/hip_bf16.h>
#include <stdint.h>

// Problem: B=64, T=512, D=2048, H=512
//   Uh   = text @ Ua + ba                 [B,H]
//   s    = tanh(frames@Wa + Uh) . Va      [B,T]
//   att  = softmax_T(s)                   [B,T]
//   out  = att . frames                   [B,D]
//
// NOTE (R3 post-mortem): measured dur_us includes ~250us of harness reset
// (1GB ws poison + frames restore) -- addressable kernel time is ~330us.
#define B_ 64
#define T_ 512
#define D_ 2048
#define H_ 512

typedef __bf16 bf16x8 __attribute__((ext_vector_type(8)));
typedef float floatx4 __attribute__((ext_vector_type(4)));

__device__ __forceinline__ unsigned short f2bf(float f) {
  unsigned int u = __float_as_uint(f);
  return (unsigned short)((u + 0x7FFFu + ((u >> 16) & 1u)) >> 16);  // RNE
}
__device__ __forceinline__ unsigned int pack2(float a, float b) {
  return (unsigned int)f2bf(a) | ((unsigned int)f2bf(b) << 16);
}
__device__ __forceinline__ float bf2f(unsigned short s) {
  return __uint_as_float((unsigned int)s << 16);
}

// async global->LDS, 16B per lane, lane i lands at ldsbase + i*16
__device__ __forceinline__ void gload16(const void* g, void* l) {
  __builtin_amdgcn_global_load_lds(
      (const __attribute__((address_space(1))) void*)g,
      (__attribute__((address_space(3))) void*)l, 16, 0, 0);
}

// ---------------------------------------------------------------------------
// Kernel 0: Wa [D][H] fp32 -> WaT [H][D] bf16  (GEMM B-operand k-contiguous)
// ---------------------------------------------------------------------------
__global__ void k_transpose_wa(const float* __restrict__ Wa,
                               unsigned short* __restrict__ WaT) {
  __shared__ float t[32][33];
  int h0 = blockIdx.x * 32;
  int d0 = blockIdx.y * 32;
  int j  = threadIdx.x & 31;
  int i0 = threadIdx.x >> 5;  // 0..7
#pragma unroll
  for (int ii = 0; ii < 4; ii++) {
    int i = i0 + ii * 8;
    t[i][j] = Wa[(size_t)(d0 + i) * H_ + h0 + j];
  }
  __syncthreads();
#pragma unroll
  for (int jj = 0; jj < 4; jj++) {
    int r = i0 + jj * 8;
    WaT[(size_t)(h0 + r) * D_ + d0 + j] = f2bf(t[j][r]);
  }
}

// ---------------------------------------------------------------------------
// Kernel 0b: frames fp32 -> bf16, streaming cast (8 elems/thread).
// ---------------------------------------------------------------------------
__global__ void k_cast(const float* __restrict__ in, unsigned short* __restrict__ out) {
  size_t i = ((size_t)blockIdx.x * 256 + threadIdx.x) * 8;
  float4 a = ((const float4*)(in + i))[0];
  float4 b = ((const float4*)(in + i))[1];
  uint4 w;
  w.x = pack2(a.x, a.y); w.y = pack2(a.z, a.w);
  w.z = pack2(b.x, b.y); w.w = pack2(b.z, b.w);
  *(uint4*)(out + i) = w;
}

// ---------------------------------------------------------------------------
// Kernel 1: split-K GEMV  UhB[b][h] += sum_{d slice} text[b][d]*Ua[d][h]
// grid (H/256, B/8, D/128) = 256 blocks. ba applied in k_scores epilogue.
// ---------------------------------------------------------------------------
__global__ void k_uh(const float* __restrict__ text, const float* __restrict__ Ua,
                     float* __restrict__ UhB) {
  __shared__ float tloc[8][128];
  const int h  = blockIdx.x * 256 + threadIdx.x;
  const int b0 = blockIdx.y * 8;
  const int d0 = blockIdx.z * 128;
  {
    int r = threadIdx.x >> 5;
    int c = threadIdx.x & 31;
#pragma unroll
    for (int j = 0; j < 4; j++)
      tloc[r][c + 32 * j] = text[(size_t)(b0 + r) * D_ + d0 + c + 32 * j];
  }
  __syncthreads();
  float acc[8] = {0.f, 0.f, 0.f, 0.f, 0.f, 0.f, 0.f, 0.f};
#pragma unroll 4
  for (int dd = 0; dd < 128; dd++) {
    float ua = Ua[(size_t)(d0 + dd) * H_ + h];
#pragma unroll
    for (int i = 0; i < 8; i++) acc[i] = fmaf(tloc[i][dd], ua, acc[i]);
  }
#pragma unroll
  for (int i = 0; i < 8; i++) atomicAdd(&UhB[(b0 + i) * H_ + h], acc[i]);
}

// ---------------------------------------------------------------------------
// Kernel 2: fused score GEMM, m97 structure.
// C[r][h] = frames[r][:] @ Wa[:][h]   (M=32768, N=512, K=2048)
// Tile 128x128xBK64, 4 waves (2x2 of 64x64), mfma 16x16x32 bf16.
// LDS unpadded stride-64 shorts (lane-order contiguous, global_load_lds).
// Epilogue: scores4[y][r] = sum_{h in block} tanh(C+UhB+ba)*Va  -- partials
// per h-block (no atomics); k_softmax sums the 4 partials.
// ---------------------------------------------------------------------------
template <bool PRECAST>
__launch_bounds__(256, 2)
__global__ void k_scores(const void* __restrict__ framesAny,
                         const unsigned short* __restrict__ WaT,
                         const float* __restrict__ UhB,
                         const float* __restrict__ Va,
                         const float* __restrict__ ba,
                         float* __restrict__ scores4) {
  __shared__ __align__(16) unsigned short ldsA[128 * 64];
  __shared__ __align__(16) unsigned short ldsB[128 * 64];
  const int tid  = threadIdx.x;
  const int lane = tid & 63, wave = tid >> 6;
  const int wm = wave >> 1, wn = wave & 1;
  const int lr = lane & 15, q = lane >> 4;
  const int mBase = blockIdx.x * 128;   // tiles never cross a batch boundary
  const int hBase = blockIdx.y * 128;

  const int sRow = lane >> 3, sOct = lane & 7;  // staging: 8 lanes/row

  floatx4 acc[4][4];
#pragma unroll
  for (int mi = 0; mi < 4; mi++)
#pragma unroll
    for (int ni = 0; ni < 4; ni++) acc[mi][ni] = (floatx4){0.f, 0.f, 0.f, 0.f};

  for (int k0 = 0; k0 < D_; k0 += 64) {
    if (PRECAST) {
      const unsigned short* fb = (const unsigned short*)framesAny;
#pragma unroll
      for (int i = 0; i < 4; i++) {
        int r0 = wave * 32 + i * 8;
        gload16(fb + (size_t)(mBase + r0 + sRow) * D_ + k0 + sOct * 8,
                &ldsA[r0 * 64]);
      }
    } else {
      const float* ff = (const float*)framesAny;
#pragma unroll
      for (int i = 0; i < 4; i++) {
        int task = i * 256 + tid;
        int m = task >> 3, oct = task & 7;
        const float* src = ff + (size_t)(mBase + m) * D_ + k0 + oct * 8;
        float4 p0 = ((const float4*)src)[0];
        float4 p1 = ((const float4*)src)[1];
        uint4 w;
        w.x = pack2(p0.x, p0.y); w.y = pack2(p0.z, p0.w);
        w.z = pack2(p1.x, p1.y); w.w = pack2(p1.z, p1.w);
        *reinterpret_cast<uint4*>(&ldsA[m * 64 + oct * 8]) = w;
      }
    }
#pragma unroll
    for (int i = 0; i < 4; i++) {
      int r0 = wave * 32 + i * 8;
      gload16(WaT + (size_t)(hBase + r0 + sRow) * D_ + k0 + sOct * 8,
              &ldsB[r0 * 64]);
    }
    __syncthreads();
#pragma unroll
    for (int kk = 0; kk < 2; kk++) {
      bf16x8 af[4], bfr[4];
#pragma unroll
      for (int mi = 0; mi < 4; mi++)
        af[mi] = *reinterpret_cast<const bf16x8*>(
            &ldsA[(wm * 64 + mi * 16 + lr) * 64 + kk * 32 + q * 8]);
#pragma unroll
      for (int ni = 0; ni < 4; ni++)
        bfr[ni] = *reinterpret_cast<const bf16x8*>(
            &ldsB[(wn * 64 + ni * 16 + lr) * 64 + kk * 32 + q * 8]);
#pragma unroll
      for (int mi = 0; mi < 4; mi++)
#pragma unroll
        for (int ni = 0; ni < 4; ni++)
          acc[mi][ni] = __builtin_amdgcn_mfma_f32_16x16x32_bf16(
              af[mi], bfr[ni], acc[mi][ni], 0, 0, 0);
    }
    __syncthreads();
  }

  // Epilogue. b is block-uniform (T=512 divisible by 128).
  const int b = mBase >> 9;
  float uhv[4], vav[4];
#pragma unroll
  for (int ni = 0; ni < 4; ni++) {
    int h = hBase + wn * 64 + ni * 16 + lr;
    uhv[ni] = UhB[b * H_ + h] + ba[h];
    vav[ni] = Va[h];
  }
  // wn=0 and wn=1 cover different h-halves of the SAME rows: combine the two
  // wave-halves via LDS-free trick: write to scores4 slot (y*2+wn).
  float* dst = scores4 + ((size_t)blockIdx.y * 2 + wn) * (B_ * T_);
  const int rowBase = mBase + wm * 64;
#pragma unroll
  for (int mi = 0; mi < 4; mi++) {
#pragma unroll
    for (int reg = 0; reg < 4; reg++) {
      float s = 0.f;
#pragma unroll
      for (int ni = 0; ni < 4; ni++) {
        float x = acc[mi][ni][reg] + uhv[ni];
        float e = __expf(2.f * x);               // tanh, inf-safe
        s += (1.f - 2.f / (e + 1.f)) * vav[ni];
      }
      s += __shfl_xor(s, 1, 16);
      s += __shfl_xor(s, 2, 16);
      s += __shfl_xor(s, 4, 16);
      s += __shfl_xor(s, 8, 16);
      if (lr == 0)
        dst[rowBase + mi * 16 + q * 4 + reg] = s;
    }
  }
}

// ---------------------------------------------------------------------------
// Kernel 3: softmax over T per batch; sums the 8 score partials first.
// grid=B, block=256 (2 elems/thread).
// ---------------------------------------------------------------------------
__global__ void k_softmax(const float* __restrict__ scores4, float* __restrict__ att) {
  __shared__ float red[4];
  int b = blockIdx.x, tid = threadIdx.x;
  int lane = tid & 63, wave = tid >> 6;
  float s0 = 0.f, s1 = 0.f;
#pragma unroll
  for (int p = 0; p < 8; p++) {
    const float* sp = scores4 + (size_t)p * (B_ * T_) + b * T_;
    s0 += sp[tid];
    s1 += sp[256 + tid];
  }
  float mx = fmaxf(s0, s1);
#pragma unroll
  for (int off = 32; off; off >>= 1) mx = fmaxf(mx, __shfl_xor(mx, off, 64));
  if (lane == 0) red[wave] = mx;
  __syncthreads();
  mx = fmaxf(fmaxf(red[0], red[1]), fmaxf(red[2], red[3]));
  __syncthreads();
  float e0 = __expf(s0 - mx), e1 = __expf(s1 - mx);
  float sm = e0 + e1;
#pragma unroll
  for (int off = 32; off; off >>= 1) sm += __shfl_xor(sm, off, 64);
  if (lane == 0) red[wave] = sm;
  __syncthreads();
  sm = red[0] + red[1] + red[2] + red[3];
  float inv = 1.f / sm;
  att[b * T_ + tid]       = e0 * inv;
  att[b * T_ + 256 + tid] = e1 * inv;
}

// ---------------------------------------------------------------------------
// Kernel 4 (R4): out[b][d] += sum_{t slice} att*framesBf (bf16 input halves
// HBM traffic; LLC-warm from k_cast). Each thread: 8 contiguous bf16 (16B),
// 256 threads cover D=2048. grid (B, 8) = 512 blocks. out memset to 0.
// ---------------------------------------------------------------------------
__global__ void k_wsum_bf(const unsigned short* __restrict__ framesBf,
                          const float* __restrict__ att, float* __restrict__ out) {
  int b  = blockIdx.x;
  int t0 = blockIdx.y * (T_ / 8);
  int d0 = threadIdx.x * 8;
  const unsigned short* fp = framesBf + (size_t)b * T_ * D_ + d0;
  const float* ap = att + b * T_ + t0;
  float acc[8] = {0.f, 0.f, 0.f, 0.f, 0.f, 0.f, 0.f, 0.f};
#pragma unroll 4
  for (int t = 0; t < T_ / 8; t++) {
    float a = ap[t];
    ushort4 lo = *(const ushort4*)(fp + (size_t)(t0 + t) * D_);
    ushort4 hi = *(const ushort4*)(fp + (size_t)(t0 + t) * D_ + 4);
    acc[0] = fmaf(a, bf2f(lo.x), acc[0]);
    acc[1] = fmaf(a, bf2f(lo.y), acc[1]);
    acc[2] = fmaf(a, bf2f(lo.z), acc[2]);
    acc[3] = fmaf(a, bf2f(lo.w), acc[3]);
    acc[4] = fmaf(a, bf2f(hi.x), acc[4]);
    acc[5] = fmaf(a, bf2f(hi.y), acc[5]);
    acc[6] = fmaf(a, bf2f(hi.z), acc[6]);
    acc[7] = fmaf(a, bf2f(hi.w), acc[7]);
  }
  float* op = out + (size_t)b * D_ + d0;
#pragma unroll
  for (int i = 0; i < 8; i++) atomicAdd(op + i, acc[i]);
}

// Fallback (no precast): fp32 frames, T-split x4, atomics.
__global__ void k_wsum(const float* __restrict__ frames, const float* __restrict__ att,
                       float* __restrict__ out) {
  int b  = blockIdx.y;
  int d0 = blockIdx.x * 1024 + threadIdx.x * 4;
  int t0 = blockIdx.z * (T_ / 4);
  const float* fp = frames + (size_t)b * T_ * D_ + d0;
  const float* ap = att + b * T_;
  float4 acc = {0.f, 0.f, 0.f, 0.f};
  for (int t = t0; t < t0 + T_ / 4; t += 4) {
    float a0 = ap[t], a1 = ap[t + 1], a2 = ap[t + 2], a3 = ap[t + 3];
    float4 v0 = *(const float4*)(fp + (size_t)(t + 0) * D_);
    float4 v1 = *(const float4*)(fp + (size_t)(t + 1) * D_);
    float4 v2 = *(const float4*)(fp + (size_t)(t + 2) * D_);
    float4 v3 = *(const float4*)(fp + (size_t)(t + 3) * D_);
    acc.x += a0 * v0.x + a1 * v1.x + a2 * v2.x + a3 * v3.x;
    acc.y += a0 * v0.y + a1 * v1.y + a2 * v2.y + a3 * v3.y;
    acc.z += a0 * v0.z + a1 * v1.z + a2 * v2.z + a3 * v3.z;
    acc.w += a0 * v0.w + a1 * v1.w + a2 * v2.w + a3 * v3.w;
  }
  float* op = out + (size_t)b * D_ + d0;
  atomicAdd(op + 0, acc.x);
  atomicAdd(op + 1, acc.y);
  atomicAdd(op + 2, acc.z);
  atomicAdd(op + 3, acc.w);
}

// ---------------------------------------------------------------------------
extern "C" void kernel_launch(void* const* d_in, const int* in_sizes, int n_in,
                              void* d_out, int out_size, void* d_ws, size_t ws_size,
                              hipStream_t stream) {
  const float* frames = (const float*)d_in[0];
  const float* text   = (const float*)d_in[1];
  const float* Wa     = (const float*)d_in[2];
  const float* Ua     = (const float*)d_in[3];
  const float* Va     = (const float*)d_in[4];
  const float* ba     = (const float*)d_in[5];
  float* out = (float*)d_out;

  const size_t FRAMES_BF_BYTES = (size_t)B_ * T_ * D_ * 2;   // 128 MB
  const bool precast = ws_size >= FRAMES_BF_BYTES + (8u << 20);

  char* ws = (char*)d_ws;
  unsigned short* framesBf = (unsigned short*)ws;  // 128 MB (precast only)
  size_t off = precast ? FRAMES_BF_BYTES : 0;
  unsigned short* WaT = (unsigned short*)(ws + off);          off += (2u << 20);
  float* UhB     = (float*)(ws + off);                        off += (128u << 10);
  float* scores4 = (float*)(ws + off);                        off += (size_t)8 * B_ * T_ * 4;
  float* att     = (float*)(ws + off);

  (void)hipMemsetAsync(UhB, 0, (size_t)B_ * H_ * sizeof(float), stream);
  (void)hipMemsetAsync(out, 0, (size_t)B_ * D_ * sizeof(float), stream);

  k_transpose_wa<<<dim3(H_ / 32, D_ / 32), 256, 0, stream>>>(Wa, WaT);
  k_uh<<<dim3(H_ / 256, B_ / 8, D_ / 128), 256, 0, stream>>>(text, Ua, UhB);
  if (precast) {
    k_cast<<<(B_ * T_ * D_) / (256 * 8), 256, 0, stream>>>(frames, framesBf);
    k_scores<true><<<dim3((B_ * T_) / 128, H_ / 128), 256, 0, stream>>>(
        framesBf, WaT, UhB, Va, ba, scores4);
    k_softmax<<<B_, 256, 0, stream>>>(scores4, att);
    k_wsum_bf<<<dim3(B_, 8), 256, 0, stream>>>(framesBf, att, out);
  } else {
    k_scores<false><<<dim3((B_ * T_) / 128, H_ / 128), 256, 0, stream>>>(
        frames, WaT, UhB, Va, ba, scores4);
    k_softmax<<<B_, 256, 0, stream>>>(scores4, att);
    k_wsum<<<dim3(D_ / 1024, B_, 4), 256, 0, stream>>>(frames, att, out);
  }
}

// Round 5
// 532.968 us; speedup vs baseline: 1.0893x; 1.0893x over previous
//
#include <hip/hip_runtime.h>
#include <hip/hip_bf16.h>
#include <stdint.h>

// Problem: B=64, T=512, D=2048, H=512
//   Uh   = text @ Ua + ba                 [B,H]
//   s    = tanh(frames@Wa + Uh) . Va      [B,T]
//   att  = softmax_T(s)                   [B,T]
//   out  = att . frames                   [B,D]
//
// Budget note: measured dur includes ~250us harness reset (1GiB ws poison +
// frames restore). Addressable kernel time ~330us (R4).
// R5 change: XOR-swizzled LDS octets in k_scores. Stride-64-short rows put
// bank-quad = octet-index (row-independent) -> 16-deep/4-quad frag reads
// (2x LDS phases). Swizzle o->o^(row&7) restores all-8-quad coverage.
#define B_ 64
#define T_ 512
#define D_ 2048
#define H_ 512

typedef __bf16 bf16x8 __attribute__((ext_vector_type(8)));
typedef float floatx4 __attribute__((ext_vector_type(4)));

__device__ __forceinline__ unsigned short f2bf(float f) {
  unsigned int u = __float_as_uint(f);
  return (unsigned short)((u + 0x7FFFu + ((u >> 16) & 1u)) >> 16);  // RNE
}
__device__ __forceinline__ unsigned int pack2(float a, float b) {
  return (unsigned int)f2bf(a) | ((unsigned int)f2bf(b) << 16);
}
__device__ __forceinline__ float bf2f(unsigned short s) {
  return __uint_as_float((unsigned int)s << 16);
}

// async global->LDS, 16B per lane, lane i lands at ldsbase + i*16
__device__ __forceinline__ void gload16(const void* g, void* l) {
  __builtin_amdgcn_global_load_lds(
      (const __attribute__((address_space(1))) void*)g,
      (__attribute__((address_space(3))) void*)l, 16, 0, 0);
}

// ---------------------------------------------------------------------------
// Kernel 0: Wa [D][H] fp32 -> WaT [H][D] bf16  (GEMM B-operand k-contiguous)
// ---------------------------------------------------------------------------
__global__ void k_transpose_wa(const float* __restrict__ Wa,
                               unsigned short* __restrict__ WaT) {
  __shared__ float t[32][33];
  int h0 = blockIdx.x * 32;
  int d0 = blockIdx.y * 32;
  int j  = threadIdx.x & 31;
  int i0 = threadIdx.x >> 5;  // 0..7
#pragma unroll
  for (int ii = 0; ii < 4; ii++) {
    int i = i0 + ii * 8;
    t[i][j] = Wa[(size_t)(d0 + i) * H_ + h0 + j];
  }
  __syncthreads();
#pragma unroll
  for (int jj = 0; jj < 4; jj++) {
    int r = i0 + jj * 8;
    WaT[(size_t)(h0 + r) * D_ + d0 + j] = f2bf(t[j][r]);
  }
}

// ---------------------------------------------------------------------------
// Kernel 0b: frames fp32 -> bf16, streaming cast (8 elems/thread).
// ---------------------------------------------------------------------------
__global__ void k_cast(const float* __restrict__ in, unsigned short* __restrict__ out) {
  size_t i = ((size_t)blockIdx.x * 256 + threadIdx.x) * 8;
  float4 a = ((const float4*)(in + i))[0];
  float4 b = ((const float4*)(in + i))[1];
  uint4 w;
  w.x = pack2(a.x, a.y); w.y = pack2(a.z, a.w);
  w.z = pack2(b.x, b.y); w.w = pack2(b.z, b.w);
  *(uint4*)(out + i) = w;
}

// ---------------------------------------------------------------------------
// Kernel 1: split-K GEMV  UhB[b][h] += sum_{d slice} text[b][d]*Ua[d][h]
// grid (H/256, B/8, D/128) = 256 blocks. ba applied in k_scores epilogue.
// ---------------------------------------------------------------------------
__global__ void k_uh(const float* __restrict__ text, const float* __restrict__ Ua,
                     float* __restrict__ UhB) {
  __shared__ float tloc[8][128];
  const int h  = blockIdx.x * 256 + threadIdx.x;
  const int b0 = blockIdx.y * 8;
  const int d0 = blockIdx.z * 128;
  {
    int r = threadIdx.x >> 5;
    int c = threadIdx.x & 31;
#pragma unroll
    for (int j = 0; j < 4; j++)
      tloc[r][c + 32 * j] = text[(size_t)(b0 + r) * D_ + d0 + c + 32 * j];
  }
  __syncthreads();
  float acc[8] = {0.f, 0.f, 0.f, 0.f, 0.f, 0.f, 0.f, 0.f};
#pragma unroll 4
  for (int dd = 0; dd < 128; dd++) {
    float ua = Ua[(size_t)(d0 + dd) * H_ + h];
#pragma unroll
    for (int i = 0; i < 8; i++) acc[i] = fmaf(tloc[i][dd], ua, acc[i]);
  }
#pragma unroll
  for (int i = 0; i < 8; i++) atomicAdd(&UhB[(b0 + i) * H_ + h], acc[i]);
}

// ---------------------------------------------------------------------------
// Kernel 2: fused score GEMM, m97 structure + XOR-swizzled LDS octets.
// C[r][h] = frames[r][:] @ Wa[:][h]   (M=32768, N=512, K=2048)
// Tile 128x128xBK64, 4 waves (2x2 of 64x64), mfma 16x16x32 bf16.
// LDS row = 8 octets of 16B; octet o of row r stored at position o^(r&7).
// DMA expresses the swizzle on the GLOBAL side (lane (row,o') fetches global
// octet o'^row); fragment reads use o' = (kk*4+q)^(lr&7) -> each q-group's
// 8 rows cover all 8 bank-quads -> conflict-free.
// Epilogue: scores4[y*2+wn][r] = sum_h tanh(C+UhB+ba)*Va (partials; softmax
// sums the 8 slots).
// ---------------------------------------------------------------------------
template <bool PRECAST>
__launch_bounds__(256, 2)
__global__ void k_scores(const void* __restrict__ framesAny,
                         const unsigned short* __restrict__ WaT,
                         const float* __restrict__ UhB,
                         const float* __restrict__ Va,
                         const float* __restrict__ ba,
                         float* __restrict__ scores4) {
  __shared__ __align__(16) unsigned short ldsA[128 * 64];
  __shared__ __align__(16) unsigned short ldsB[128 * 64];
  const int tid  = threadIdx.x;
  const int lane = tid & 63, wave = tid >> 6;
  const int wm = wave >> 1, wn = wave & 1;
  const int lr = lane & 15, q = lane >> 4;
  const int mBase = blockIdx.x * 128;   // tiles never cross a batch boundary
  const int hBase = blockIdx.y * 128;

  // staging: 8 lanes/row; lane (sRow, o') fetches global octet o'^sRow
  const int sRow  = lane >> 3;                 // 0..7
  const int sOctG = (lane & 7) ^ sRow;         // swizzled global octet

  floatx4 acc[4][4];
#pragma unroll
  for (int mi = 0; mi < 4; mi++)
#pragma unroll
    for (int ni = 0; ni < 4; ni++) acc[mi][ni] = (floatx4){0.f, 0.f, 0.f, 0.f};

  for (int k0 = 0; k0 < D_; k0 += 64) {
    if (PRECAST) {
      const unsigned short* fb = (const unsigned short*)framesAny;
#pragma unroll
      for (int i = 0; i < 4; i++) {
        int r0 = wave * 32 + i * 8;
        gload16(fb + (size_t)(mBase + r0 + sRow) * D_ + k0 + sOctG * 8,
                &ldsA[r0 * 64]);
      }
    } else {
      const float* ff = (const float*)framesAny;
#pragma unroll
      for (int i = 0; i < 4; i++) {
        int task = i * 256 + tid;
        int m = task >> 3, oct = task & 7;
        const float* src = ff + (size_t)(mBase + m) * D_ + k0 + oct * 8;
        float4 p0 = ((const float4*)src)[0];
        float4 p1 = ((const float4*)src)[1];
        uint4 w;
        w.x = pack2(p0.x, p0.y); w.y = pack2(p0.z, p0.w);
        w.z = pack2(p1.x, p1.y); w.w = pack2(p1.z, p1.w);
        *reinterpret_cast<uint4*>(&ldsA[m * 64 + (oct ^ (m & 7)) * 8]) = w;
      }
    }
#pragma unroll
    for (int i = 0; i < 4; i++) {
      int r0 = wave * 32 + i * 8;
      gload16(WaT + (size_t)(hBase + r0 + sRow) * D_ + k0 + sOctG * 8,
              &ldsB[r0 * 64]);
    }
    __syncthreads();
#pragma unroll
    for (int kk = 0; kk < 2; kk++) {
      bf16x8 af[4], bfr[4];
      const int ob = (kk * 4 + q) ^ (lr & 7);  // swizzled octet for frag read
#pragma unroll
      for (int mi = 0; mi < 4; mi++)
        af[mi] = *reinterpret_cast<const bf16x8*>(
            &ldsA[(wm * 64 + mi * 16 + lr) * 64 + ob * 8]);
#pragma unroll
      for (int ni = 0; ni < 4; ni++)
        bfr[ni] = *reinterpret_cast<const bf16x8*>(
            &ldsB[(wn * 64 + ni * 16 + lr) * 64 + ob * 8]);
#pragma unroll
      for (int mi = 0; mi < 4; mi++)
#pragma unroll
        for (int ni = 0; ni < 4; ni++)
          acc[mi][ni] = __builtin_amdgcn_mfma_f32_16x16x32_bf16(
              af[mi], bfr[ni], acc[mi][ni], 0, 0, 0);
    }
    __syncthreads();
  }

  // Epilogue. b is block-uniform (T=512 divisible by 128).
  const int b = mBase >> 9;
  float uhv[4], vav[4];
#pragma unroll
  for (int ni = 0; ni < 4; ni++) {
    int h = hBase + wn * 64 + ni * 16 + lr;
    uhv[ni] = UhB[b * H_ + h] + ba[h];
    vav[ni] = Va[h];
  }
  float* dst = scores4 + ((size_t)blockIdx.y * 2 + wn) * (B_ * T_);
  const int rowBase = mBase + wm * 64;
#pragma unroll
  for (int mi = 0; mi < 4; mi++) {
#pragma unroll
    for (int reg = 0; reg < 4; reg++) {
      float s = 0.f;
#pragma unroll
      for (int ni = 0; ni < 4; ni++) {
        float x = acc[mi][ni][reg] + uhv[ni];
        float e = __expf(2.f * x);               // tanh, inf-safe
        s += (1.f - 2.f / (e + 1.f)) * vav[ni];
      }
      s += __shfl_xor(s, 1, 16);
      s += __shfl_xor(s, 2, 16);
      s += __shfl_xor(s, 4, 16);
      s += __shfl_xor(s, 8, 16);
      if (lr == 0)
        dst[rowBase + mi * 16 + q * 4 + reg] = s;
    }
  }
}

// ---------------------------------------------------------------------------
// Kernel 3: softmax over T per batch; sums the 8 score partials first.
// grid=B, block=256 (2 elems/thread).
// ---------------------------------------------------------------------------
__global__ void k_softmax(const float* __restrict__ scores4, float* __restrict__ att) {
  __shared__ float red[4];
  int b = blockIdx.x, tid = threadIdx.x;
  int lane = tid & 63, wave = tid >> 6;
  float s0 = 0.f, s1 = 0.f;
#pragma unroll
  for (int p = 0; p < 8; p++) {
    const float* sp = scores4 + (size_t)p * (B_ * T_) + b * T_;
    s0 += sp[tid];
    s1 += sp[256 + tid];
  }
  float mx = fmaxf(s0, s1);
#pragma unroll
  for (int off = 32; off; off >>= 1) mx = fmaxf(mx, __shfl_xor(mx, off, 64));
  if (lane == 0) red[wave] = mx;
  __syncthreads();
  mx = fmaxf(fmaxf(red[0], red[1]), fmaxf(red[2], red[3]));
  __syncthreads();
  float e0 = __expf(s0 - mx), e1 = __expf(s1 - mx);
  float sm = e0 + e1;
#pragma unroll
  for (int off = 32; off; off >>= 1) sm += __shfl_xor(sm, off, 64);
  if (lane == 0) red[wave] = sm;
  __syncthreads();
  sm = red[0] + red[1] + red[2] + red[3];
  float inv = 1.f / sm;
  att[b * T_ + tid]       = e0 * inv;
  att[b * T_ + 256 + tid] = e1 * inv;
}

// ---------------------------------------------------------------------------
// Kernel 4: out[b][d] += sum_{t slice} att*framesBf (bf16 halves HBM).
// grid (B, 8) = 512 blocks; 8 contiguous bf16 per thread. out memset to 0.
// ---------------------------------------------------------------------------
__global__ void k_wsum_bf(const unsigned short* __restrict__ framesBf,
                          const float* __restrict__ att, float* __restrict__ out) {
  int b  = blockIdx.x;
  int t0 = blockIdx.y * (T_ / 8);
  int d0 = threadIdx.x * 8;
  const unsigned short* fp = framesBf + (size_t)b * T_ * D_ + d0;
  const float* ap = att + b * T_ + t0;
  float acc[8] = {0.f, 0.f, 0.f, 0.f, 0.f, 0.f, 0.f, 0.f};
#pragma unroll 4
  for (int t = 0; t < T_ / 8; t++) {
    float a = ap[t];
    ushort4 lo = *(const ushort4*)(fp + (size_t)(t0 + t) * D_);
    ushort4 hi = *(const ushort4*)(fp + (size_t)(t0 + t) * D_ + 4);
    acc[0] = fmaf(a, bf2f(lo.x), acc[0]);
    acc[1] = fmaf(a, bf2f(lo.y), acc[1]);
    acc[2] = fmaf(a, bf2f(lo.z), acc[2]);
    acc[3] = fmaf(a, bf2f(lo.w), acc[3]);
    acc[4] = fmaf(a, bf2f(hi.x), acc[4]);
    acc[5] = fmaf(a, bf2f(hi.y), acc[5]);
    acc[6] = fmaf(a, bf2f(hi.z), acc[6]);
    acc[7] = fmaf(a, bf2f(hi.w), acc[7]);
  }
  float* op = out + (size_t)b * D_ + d0;
#pragma unroll
  for (int i = 0; i < 8; i++) atomicAdd(op + i, acc[i]);
}

// Fallback (no precast): fp32 frames, T-split x4, atomics.
__global__ void k_wsum(const float* __restrict__ frames, const float* __restrict__ att,
                       float* __restrict__ out) {
  int b  = blockIdx.y;
  int d0 = blockIdx.x * 1024 + threadIdx.x * 4;
  int t0 = blockIdx.z * (T_ / 4);
  const float* fp = frames + (size_t)b * T_ * D_ + d0;
  const float* ap = att + b * T_;
  float4 acc = {0.f, 0.f, 0.f, 0.f};
  for (int t = t0; t < t0 + T_ / 4; t += 4) {
    float a0 = ap[t], a1 = ap[t + 1], a2 = ap[t + 2], a3 = ap[t + 3];
    float4 v0 = *(const float4*)(fp + (size_t)(t + 0) * D_);
    float4 v1 = *(const float4*)(fp + (size_t)(t + 1) * D_);
    float4 v2 = *(const float4*)(fp + (size_t)(t + 2) * D_);
    float4 v3 = *(const float4*)(fp + (size_t)(t + 3) * D_);
    acc.x += a0 * v0.x + a1 * v1.x + a2 * v2.x + a3 * v3.x;
    acc.y += a0 * v0.y + a1 * v1.y + a2 * v2.y + a3 * v3.y;
    acc.z += a0 * v0.z + a1 * v1.z + a2 * v2.z + a3 * v3.z;
    acc.w += a0 * v0.w + a1 * v1.w + a2 * v2.w + a3 * v3.w;
  }
  float* op = out + (size_t)b * D_ + d0;
  atomicAdd(op + 0, acc.x);
  atomicAdd(op + 1, acc.y);
  atomicAdd(op + 2, acc.z);
  atomicAdd(op + 3, acc.w);
}

// ---------------------------------------------------------------------------
extern "C" void kernel_launch(void* const* d_in, const int* in_sizes, int n_in,
                              void* d_out, int out_size, void* d_ws, size_t ws_size,
                              hipStream_t stream) {
  const float* frames = (const float*)d_in[0];
  const float* text   = (const float*)d_in[1];
  const float* Wa     = (const float*)d_in[2];
  const float* Ua     = (const float*)d_in[3];
  const float* Va     = (const float*)d_in[4];
  const float* ba     = (const float*)d_in[5];
  float* out = (float*)d_out;

  const size_t FRAMES_BF_BYTES = (size_t)B_ * T_ * D_ * 2;   // 128 MB
  const bool precast = ws_size >= FRAMES_BF_BYTES + (8u << 20);

  char* ws = (char*)d_ws;
  unsigned short* framesBf = (unsigned short*)ws;  // 128 MB (precast only)
  size_t off = precast ? FRAMES_BF_BYTES : 0;
  unsigned short* WaT = (unsigned short*)(ws + off);          off += (2u << 20);
  float* UhB     = (float*)(ws + off);                        off += (128u << 10);
  float* scores4 = (float*)(ws + off);                        off += (size_t)8 * B_ * T_ * 4;
  float* att     = (float*)(ws + off);

  (void)hipMemsetAsync(UhB, 0, (size_t)B_ * H_ * sizeof(float), stream);
  (void)hipMemsetAsync(out, 0, (size_t)B_ * D_ * sizeof(float), stream);

  k_transpose_wa<<<dim3(H_ / 32, D_ / 32), 256, 0, stream>>>(Wa, WaT);
  k_uh<<<dim3(H_ / 256, B_ / 8, D_ / 128), 256, 0, stream>>>(text, Ua, UhB);
  if (precast) {
    k_cast<<<(B_ * T_ * D_) / (256 * 8), 256, 0, stream>>>(frames, framesBf);
    k_scores<true><<<dim3((B_ * T_) / 128, H_ / 128), 256, 0, stream>>>(
        framesBf, WaT, UhB, Va, ba, scores4);
    k_softmax<<<B_, 256, 0, stream>>>(scores4, att);
    k_wsum_bf<<<dim3(B_, 8), 256, 0, stream>>>(framesBf, att, out);
  } else {
    k_scores<false><<<dim3((B_ * T_) / 128, H_ / 128), 256, 0, stream>>>(
        frames, WaT, UhB, Va, ba, scores4);
    k_softmax<<<B_, 256, 0, stream>>>(scores4, att);
    k_wsum<<<dim3(D_ / 1024, B_, 4), 256, 0, stream>>>(frames, att, out);
  }
}